// Round 6
// baseline (183.758 us; speedup 1.0000x reference)
//
#include <hip/hip_runtime.h>
#include <hip/hip_bf16.h>

// GraphSage: h1 = segsum(val * x[dst] -> src) / deg; out = [x, h1norm] @ W
// N=50000, D=128, E=800000, W [256,128] fp32, out [N,128] fp32.
// Pipeline: xconv+hist -> scan1 -> scan2+wconv -> scan3
//           -> bin (8 XCD-partition queues) -> fill2 (XCD-local scatter)
//           -> bf16 gather (unroll 4) -> bf16 MFMA GEMM.

#define N_NODES 50000
#define DIM 128
#define N_EDGES 800000
#define NB_SCAN 196   // ceil(N_NODES/256)
#define EB 3125       // ceil(N_EDGES/256)
#define XB 6250       // N_NODES*DIM/4/256
#define NPART 8
#define PART_DIV 6250 // nodes per partition
#define QCAP 200000   // queue entries per partition (avg 100K, huge margin)
#define FILL2_GRID 2048

typedef __attribute__((ext_vector_type(8))) short bf16x8;
typedef __attribute__((ext_vector_type(4))) float f32x4;

// round-to-nearest-even f32 -> bf16 bits
__device__ __forceinline__ unsigned short f2bf(float f) {
    unsigned int u = __float_as_uint(f);
    unsigned int r = (u + 0x7FFFu + ((u >> 16) & 1u)) >> 16;
    return (unsigned short)r;
}
__device__ __forceinline__ float bf_lo(unsigned int u) {
    return __uint_as_float(u << 16);
}
__device__ __forceinline__ float bf_hi(unsigned int u) {
    return __uint_as_float(u & 0xFFFF0000u);
}

// ---------------------------------------------------------------------------
// Fused: x f32 -> bf16 convert  +  edge-source histogram.
// ---------------------------------------------------------------------------
__global__ __launch_bounds__(256) void xconv_hist_kernel(
    const float* __restrict__ x, unsigned short* __restrict__ xh,
    const int* __restrict__ esrc, int* __restrict__ cnt)
{
    int i = blockIdx.x * 256 + threadIdx.x;
    if (i < N_NODES * DIM / 4) {
        float4 v = reinterpret_cast<const float4*>(x)[i];
        ushort4 o;
        o.x = f2bf(v.x); o.y = f2bf(v.y); o.z = f2bf(v.z); o.w = f2bf(v.w);
        reinterpret_cast<ushort4*>(xh)[i] = o;
    }
    if (blockIdx.x < EB) {
        int e = blockIdx.x * 256 + threadIdx.x;
        if (e < N_EDGES) atomicAdd(&cnt[esrc[e]], 1);
    }
}

// ---------------------------------------------------------------------------
// Scan level 1
// ---------------------------------------------------------------------------
__global__ __launch_bounds__(256) void scan1_kernel(
    const int* __restrict__ cnt, int* __restrict__ rowoff, int* __restrict__ bsum)
{
    __shared__ int s[256];
    int t = threadIdx.x;
    int i = blockIdx.x * 256 + t;
    int v = (i < N_NODES) ? cnt[i] : 0;
    s[t] = v;
    __syncthreads();
    #pragma unroll
    for (int off = 1; off < 256; off <<= 1) {
        int tmp = (t >= off) ? s[t - off] : 0;
        __syncthreads();
        s[t] += tmp;
        __syncthreads();
    }
    if (i < N_NODES) rowoff[i] = s[t] - v;
    if (t == 255) bsum[blockIdx.x] = s[255];
}

// ---------------------------------------------------------------------------
// Fused: block 0 scans bsum; blocks 1..16 pack W into MFMA B-fragment order.
// ---------------------------------------------------------------------------
__global__ __launch_bounds__(256) void scan2_wconv_kernel(
    int* __restrict__ bsum, const float* __restrict__ W,
    unsigned short* __restrict__ wfrag)
{
    if (blockIdx.x == 0) {
        __shared__ int s[256];
        int t = threadIdx.x;
        int v = (t < NB_SCAN) ? bsum[t] : 0;
        s[t] = v;
        __syncthreads();
        #pragma unroll
        for (int off = 1; off < 256; off <<= 1) {
            int tmp = (t >= off) ? s[t - off] : 0;
            __syncthreads();
            s[t] += tmp;
            __syncthreads();
        }
        if (t < NB_SCAN) bsum[t] = s[t] - v;
    } else {
        int idx = (blockIdx.x - 1) * 256 + threadIdx.x;   // 0..4095
        int l  = idx & 63;
        int ks = (idx >> 6) & 7;
        int nt = idx >> 9;
        int col  = nt * 16 + (l & 15);
        int krow = ks * 32 + (l >> 4) * 8;
        ushort4 lo, hi;
        lo.x = f2bf(W[(krow + 0) * DIM + col]);
        lo.y = f2bf(W[(krow + 1) * DIM + col]);
        lo.z = f2bf(W[(krow + 2) * DIM + col]);
        lo.w = f2bf(W[(krow + 3) * DIM + col]);
        hi.x = f2bf(W[(krow + 4) * DIM + col]);
        hi.y = f2bf(W[(krow + 5) * DIM + col]);
        hi.z = f2bf(W[(krow + 6) * DIM + col]);
        hi.w = f2bf(W[(krow + 7) * DIM + col]);
        reinterpret_cast<ushort4*>(wfrag)[idx * 2 + 0] = lo;
        reinterpret_cast<ushort4*>(wfrag)[idx * 2 + 1] = hi;
    }
}

__global__ __launch_bounds__(256) void scan3_kernel(
    int* __restrict__ rowoff, const int* __restrict__ bsum)
{
    int i = blockIdx.x * 256 + threadIdx.x;
    if (i < N_NODES) rowoff[i] += bsum[blockIdx.x];
}

// ---------------------------------------------------------------------------
// Bin: edges -> 8 partition queues, packed 8B entries {src|dst<<16, val_f32}.
// Per-tile LDS histogram gives per-partition ranks; one global cursor bump
// per (tile, partition) -> contiguous coalesced runs in each queue.
// ---------------------------------------------------------------------------
__global__ __launch_bounds__(256) void bin_kernel(
    const int* __restrict__ esrc, const int* __restrict__ edst,
    const float* __restrict__ eval,
    int* __restrict__ qcount, int2* __restrict__ queue)
{
    __shared__ int hist[NPART];
    __shared__ int base[NPART];

    int t = threadIdx.x;
    int e = blockIdx.x * 256 + t;
    bool valid = (e < N_EDGES);

    int src = 0, dst = 0, P = 0, rank = 0;
    float v = 0.0f;
    if (t < NPART) hist[t] = 0;
    __syncthreads();
    if (valid) {
        src = esrc[e];
        dst = edst[e];
        v   = eval[e];
        P   = src / PART_DIV;
        if (P >= NPART) P = NPART - 1;
        rank = atomicAdd(&hist[P], 1);
    }
    __syncthreads();
    if (t < NPART) base[t] = atomicAdd(&qcount[t], hist[t]);
    __syncthreads();
    if (valid) {
        int pos = base[P] + rank;
        if (pos < QCAP) {
            int2 pk;
            pk.x = src | (dst << 16);   // both < 2^16; sign bit may be set
            pk.y = __float_as_int(v);
            queue[(size_t)P * QCAP + pos] = pk;
        }
    }
}

// ---------------------------------------------------------------------------
// Fill2: XCD-local scatter. Block handles partition P = blockIdx&7; under the
// empirical blockIdx%8 -> XCD round-robin, all writes to partition P's csr
// region come from one XCD -> full-line L2 accumulation, minimal write-amp.
// After this kernel, rowoff[i] == end of row i.
// ---------------------------------------------------------------------------
__global__ __launch_bounds__(256) void fill2_kernel(
    const int2* __restrict__ queue, const int* __restrict__ qcount,
    int* __restrict__ rowoff, int2* __restrict__ csr)
{
    int P = blockIdx.x & 7;
    int w = blockIdx.x >> 3;
    int n = qcount[P];
    const int2* q = queue + (size_t)P * QCAP;
    const int stride = (FILL2_GRID / 8) * 256;

    for (int i = w * 256 + threadIdx.x; i < n; i += stride) {
        int2 e = q[i];
        int src = e.x & 0xFFFF;
        int dst = (int)(((unsigned int)e.x) >> 16);   // UNSIGNED shift: dst>=32768 sets sign bit
        int p = atomicAdd(&rowoff[src], 1);
        int2 pk;
        pk.x = dst;
        pk.y = e.y;
        csr[p] = pk;
    }
}

// ---------------------------------------------------------------------------
// Gather: one wave per node; unroll 4 for MLP on the random x-row loads.
// start = rowoff[node-1] (0 for node 0), end = rowoff[node].
// ---------------------------------------------------------------------------
__global__ __launch_bounds__(256) void gather_kernel(
    const unsigned short* __restrict__ xh,
    const int2* __restrict__ csr,
    const int* __restrict__ rowoff,
    unsigned short* __restrict__ h1h)
{
    int node = blockIdx.x * 4 + (threadIdx.x >> 6);
    node = __builtin_amdgcn_readfirstlane(node);
    int lane = threadIdx.x & 63;

    int end = rowoff[node];
    int p   = (node == 0) ? 0 : rowoff[node - 1];

    const unsigned int* xu = reinterpret_cast<const unsigned int*>(xh);

    float ax = 0.0f, ay = 0.0f, dg = 0.0f;
    for (; p + 3 < end; p += 4) {
        int2 e0 = csr[p];
        int2 e1 = csr[p + 1];
        int2 e2 = csr[p + 2];
        int2 e3 = csr[p + 3];
        float v0 = __int_as_float(e0.y);
        float v1 = __int_as_float(e1.y);
        float v2 = __int_as_float(e2.y);
        float v3 = __int_as_float(e3.y);
        unsigned int u0 = xu[e0.x * 64 + lane];
        unsigned int u1 = xu[e1.x * 64 + lane];
        unsigned int u2 = xu[e2.x * 64 + lane];
        unsigned int u3 = xu[e3.x * 64 + lane];
        ax += v0 * bf_lo(u0) + v1 * bf_lo(u1) + v2 * bf_lo(u2) + v3 * bf_lo(u3);
        ay += v0 * bf_hi(u0) + v1 * bf_hi(u1) + v2 * bf_hi(u2) + v3 * bf_hi(u3);
        dg += v0 + v1 + v2 + v3;
    }
    for (; p < end; ++p) {
        int2 e0 = csr[p];
        float v0 = __int_as_float(e0.y);
        unsigned int u0 = xu[e0.x * 64 + lane];
        ax += v0 * bf_lo(u0);
        ay += v0 * bf_hi(u0);
        dg += v0;
    }
    float inv = 1.0f / (dg + 1e-6f);
    unsigned int o = ((unsigned int)f2bf(ay * inv) << 16) | f2bf(ax * inv);
    reinterpret_cast<unsigned int*>(h1h)[node * 64 + lane] = o;
}

// ---------------------------------------------------------------------------
// MFMA GEMM: out[N,128] = [xh | h1h] @ W (bf16 in, fp32 out).
// ---------------------------------------------------------------------------
__global__ __launch_bounds__(256) void gemm_kernel(
    const unsigned short* __restrict__ xh,
    const unsigned short* __restrict__ h1h,
    const unsigned short* __restrict__ wfrag,
    float* __restrict__ out)
{
    int l   = threadIdx.x & 63;
    int wid = threadIdx.x >> 6;
    int r0  = blockIdx.x * 64;
    int lr  = l & 15;
    int lk  = l >> 4;

    f32x4 acc[4][2];
    #pragma unroll
    for (int mf = 0; mf < 4; ++mf)
        #pragma unroll
        for (int nf = 0; nf < 2; ++nf)
            acc[mf][nf] = (f32x4){0.f, 0.f, 0.f, 0.f};

    #pragma unroll
    for (int ks = 0; ks < 8; ++ks) {
        const unsigned short* src = (ks < 4) ? xh : h1h;
        int coff = (ks & 3) * 32 + lk * 8;

        bf16x8 a[4];
        #pragma unroll
        for (int mf = 0; mf < 4; ++mf) {
            int row = r0 + mf * 16 + lr;
            if (row >= N_NODES) row = N_NODES - 1;
            a[mf] = *reinterpret_cast<const bf16x8*>(src + (size_t)row * DIM + coff);
        }
        bf16x8 b[2];
        #pragma unroll
        for (int nf = 0; nf < 2; ++nf) {
            int nt = wid * 2 + nf;
            b[nf] = *reinterpret_cast<const bf16x8*>(
                wfrag + ((size_t)((nt * 8 + ks) * 64 + l)) * 8);
        }
        #pragma unroll
        for (int mf = 0; mf < 4; ++mf)
            #pragma unroll
            for (int nf = 0; nf < 2; ++nf)
                acc[mf][nf] = __builtin_amdgcn_mfma_f32_16x16x32_bf16(
                    a[mf], b[nf], acc[mf][nf], 0, 0, 0);
    }

    #pragma unroll
    for (int mf = 0; mf < 4; ++mf) {
        #pragma unroll
        for (int nf = 0; nf < 2; ++nf) {
            int col = wid * 32 + nf * 16 + lr;
            #pragma unroll
            for (int rr = 0; rr < 4; ++rr) {
                int row = r0 + mf * 16 + lk * 4 + rr;
                if (row < N_NODES)
                    out[(size_t)row * DIM + col] = acc[mf][nf][rr];
            }
        }
    }
}

extern "C" void kernel_launch(void* const* d_in, const int* in_sizes, int n_in,
                              void* d_out, int out_size, void* d_ws, size_t ws_size,
                              hipStream_t stream) {
    const float* x    = (const float*)d_in[0];
    const float* W    = (const float*)d_in[1];
    const int*   esrc = (const int*)d_in[2];
    const int*   edst = (const int*)d_in[3];
    const float* eval = (const float*)d_in[4];
    float* out = (float*)d_out;

    // ws layout (32,401,016 B total; <= proven 32,401,024):
    //   xh     : N*DIM bf16 (12.8 MB)            @ 0
    //   h1h    : N*DIM bf16 (12.8 MB)            @ 12.8 MB   (aliased by queue)
    //   cnt    : 50000 ints (aliased by wfrag)   @ 25.6 MB
    //   rowoff : 50000 ints
    //   bsum   : 196 ints
    //   qcount : 8 ints
    //   csr    : E int2 (6.4 MB)
    unsigned short* xh  = (unsigned short*)d_ws;
    unsigned short* h1h = xh + (size_t)N_NODES * DIM;
    int2* queue = (int2*)h1h;                       // alias (dead before gather)
    int*  cnt    = (int*)(h1h + (size_t)N_NODES * DIM);
    int*  rowoff = cnt + N_NODES;
    int*  bsum   = rowoff + N_NODES;
    int*  qcount = bsum + NB_SCAN;
    int2* csr    = (int2*)(qcount + NPART);
    unsigned short* wfrag = (unsigned short*)cnt;   // alias: cnt dead after scan1

    hipMemsetAsync(cnt, 0, (size_t)N_NODES * sizeof(int), stream);
    hipMemsetAsync(qcount, 0, NPART * sizeof(int), stream);
    xconv_hist_kernel<<<XB, 256, 0, stream>>>(x, xh, esrc, cnt);
    scan1_kernel<<<NB_SCAN, 256, 0, stream>>>(cnt, rowoff, bsum);
    scan2_wconv_kernel<<<17, 256, 0, stream>>>(bsum, W, wfrag);
    scan3_kernel<<<NB_SCAN, 256, 0, stream>>>(rowoff, bsum);
    bin_kernel<<<EB, 256, 0, stream>>>(esrc, edst, eval, qcount, queue);
    fill2_kernel<<<FILL2_GRID, 256, 0, stream>>>(queue, qcount, rowoff, csr);
    gather_kernel<<<N_NODES / 4, 256, 0, stream>>>(xh, csr, rowoff, h1h);
    gemm_kernel<<<(N_NODES + 63) / 64, 256, 0, stream>>>(xh, h1h, wfrag, out);
}

// Round 7
// 106.115 us; speedup vs baseline: 1.7317x; 1.7317x over previous
//
#include <hip/hip_runtime.h>
#include <hip/hip_bf16.h>

// GraphSage: h1 = segsum(val * x[dst] -> src) / deg; out = [x, h1norm] @ W
// N=50000, D=128, E=800000, W [256,128] fp32, out [N,128] fp32.
//
// Round-7 structure (no per-edge global atomics):
//   memset(qcount, 4KB)
//   fused_prep: blocks [0,98) bin edges into 1024 partitions (49 nodes each)
//               blocks [98,6348) convert x f32 -> bf16
//               blocks [6348,6364) pack W into MFMA B-fragment order
//   gather_local: 1024 blocks; per-partition LDS CSR (hist/scan/reorder in
//               LDS), then wave-per-node row accumulation; writes bf16 h1h.
//   gemm: bf16 MFMA, out = [xh | h1h] @ W.

#define N_NODES 50000
#define DIM 128
#define N_EDGES 800000
#define XB 6250         // convert blocks: N*DIM/4/256
#define NPART 1024      // partitions
#define PN 49           // nodes per partition (1024*49 = 50176 >= 50000)
#define QCAP 1100       // per-partition queue capacity (mean 781, +11 sigma)
#define BIN_T 8192      // edges per bin tile
#define BIN_TILES 98    // ceil(800000/8192)
#define WCONV_B 16      // 16*256 = 4096 threads for W pack

typedef __attribute__((ext_vector_type(8))) short bf16x8;
typedef __attribute__((ext_vector_type(4))) float f32x4;

// round-to-nearest-even f32 -> bf16 bits
__device__ __forceinline__ unsigned short f2bf(float f) {
    unsigned int u = __float_as_uint(f);
    unsigned int r = (u + 0x7FFFu + ((u >> 16) & 1u)) >> 16;
    return (unsigned short)r;
}
__device__ __forceinline__ float bf_lo(unsigned int u) {
    return __uint_as_float(u << 16);
}
__device__ __forceinline__ float bf_hi(unsigned int u) {
    return __uint_as_float(u & 0xFFFF0000u);
}

// ---------------------------------------------------------------------------
// Fused prep kernel.
// ---------------------------------------------------------------------------
__global__ __launch_bounds__(256) void fused_prep_kernel(
    const float* __restrict__ x, unsigned short* __restrict__ xh,
    const int* __restrict__ esrc, const int* __restrict__ edst,
    const float* __restrict__ eval,
    int* __restrict__ qcount, int2* __restrict__ queue,
    const float* __restrict__ W, unsigned short* __restrict__ wfrag)
{
    int b = blockIdx.x;
    int t = threadIdx.x;

    if (b < BIN_TILES) {
        // ---- bin tile: BIN_T edges -> 1024 partition queues ----
        __shared__ int hist[NPART];
        for (int i = t; i < NPART; i += 256) hist[i] = 0;
        __syncthreads();

        int e0 = b * BIN_T;
        // pass 1: count
        for (int i = t; i < BIN_T; i += 256) {
            int e = e0 + i;
            if (e < N_EDGES) {
                int s = esrc[e];
                int P = s / PN;
                atomicAdd(&hist[P], 1);
            }
        }
        __syncthreads();
        // reserve global ranges; hist[P] becomes the running cursor
        for (int i = t; i < NPART; i += 256) {
            int c = hist[i];
            hist[i] = (c > 0) ? atomicAdd(&qcount[i], c) : 0;
        }
        __syncthreads();
        // pass 2: place (re-read edges; L2-hot)
        for (int i = t; i < BIN_T; i += 256) {
            int e = e0 + i;
            if (e < N_EDGES) {
                int s = esrc[e];
                int P = s / PN;
                int ls = s - P * PN;               // 0..48 (6 bits)
                int pos = atomicAdd(&hist[P], 1);
                if (pos < QCAP) {
                    int2 pk;
                    pk.x = ls | (edst[e] << 6);    // 22 bits, positive
                    pk.y = __float_as_int(eval[e]);
                    queue[(size_t)P * QCAP + pos] = pk;
                }
            }
        }
        return;
    }

    if (b < BIN_TILES + XB) {
        // ---- convert: one float4 per thread ----
        int i = (b - BIN_TILES) * 256 + t;        // < 1,600,000
        float4 v = reinterpret_cast<const float4*>(x)[i];
        ushort4 o;
        o.x = f2bf(v.x); o.y = f2bf(v.y); o.z = f2bf(v.z); o.w = f2bf(v.w);
        reinterpret_cast<ushort4*>(xh)[i] = o;
        return;
    }

    // ---- W pack into MFMA B-fragment order ----
    // Wfrag[((nt*8+ks)*64+l)*8 + j] = bf16(W[ks*32+(l>>4)*8+j][nt*16+(l&15)])
    {
        int idx = (b - BIN_TILES - XB) * 256 + t;  // 0..4095
        int l  = idx & 63;
        int ks = (idx >> 6) & 7;
        int nt = idx >> 9;
        int col  = nt * 16 + (l & 15);
        int krow = ks * 32 + (l >> 4) * 8;
        ushort4 lo, hi;
        lo.x = f2bf(W[(krow + 0) * DIM + col]);
        lo.y = f2bf(W[(krow + 1) * DIM + col]);
        lo.z = f2bf(W[(krow + 2) * DIM + col]);
        lo.w = f2bf(W[(krow + 3) * DIM + col]);
        hi.x = f2bf(W[(krow + 4) * DIM + col]);
        hi.y = f2bf(W[(krow + 5) * DIM + col]);
        hi.z = f2bf(W[(krow + 6) * DIM + col]);
        hi.w = f2bf(W[(krow + 7) * DIM + col]);
        reinterpret_cast<ushort4*>(wfrag)[idx * 2 + 0] = lo;
        reinterpret_cast<ushort4*>(wfrag)[idx * 2 + 1] = hi;
    }
}

// ---------------------------------------------------------------------------
// Gather with per-partition LDS CSR. One block per partition (49 nodes).
// ---------------------------------------------------------------------------
__global__ __launch_bounds__(256) void gather_local_kernel(
    const unsigned short* __restrict__ xh,
    const int2* __restrict__ queue, const int* __restrict__ qcount,
    unsigned short* __restrict__ h1h)
{
    __shared__ int cnt[64];
    __shared__ int off[64];
    __shared__ int cur[64];
    __shared__ int2 csr[QCAP];

    int b = blockIdx.x;
    int t = threadIdx.x;

    int n = qcount[b];
    if (n > QCAP) n = QCAP;    // never triggers for this input; memory safety
    const int2* q = queue + (size_t)b * QCAP;

    if (t < 64) cnt[t] = 0;
    __syncthreads();

    // pass 1: local histogram
    for (int i = t; i < n; i += 256) {
        int ls = q[i].x & 63;
        atomicAdd(&cnt[ls], 1);
    }
    __syncthreads();

    // Hillis-Steele inclusive scan over 64 slots -> exclusive off
    if (t < 64) off[t] = cnt[t];
    __syncthreads();
    #pragma unroll
    for (int d = 1; d < 64; d <<= 1) {
        int v = 0;
        if (t < 64 && t >= d) v = off[t - d];
        __syncthreads();
        if (t < 64) off[t] += v;
        __syncthreads();
    }
    if (t < 64) {
        int ex = off[t] - cnt[t];
        off[t] = ex;
        cur[t] = ex;
    }
    __syncthreads();

    // pass 2: reorder into LDS CSR {dst, val_bits}
    for (int i = t; i < n; i += 256) {
        int2 e = q[i];
        int ls = e.x & 63;
        int pos = atomicAdd(&cur[ls], 1);
        int2 pk;
        pk.x = (int)(((unsigned int)e.x) >> 6);   // dst (unsigned shift!)
        pk.y = e.y;
        csr[pos] = pk;
    }
    __syncthreads();

    // gather: wave w handles local nodes w, w+4, ...
    int wid  = t >> 6;
    int lane = t & 63;
    const unsigned int* xu = reinterpret_cast<const unsigned int*>(xh);

    for (int ls = wid; ls < PN; ls += 4) {
        int node = b * PN + ls;
        if (node >= N_NODES) break;
        int s  = off[ls];
        int eN = s + cnt[ls];

        float ax = 0.0f, ay = 0.0f, dg = 0.0f;
        int j = s;
        for (; j + 3 < eN; j += 4) {
            int2 e0 = csr[j];
            int2 e1 = csr[j + 1];
            int2 e2 = csr[j + 2];
            int2 e3 = csr[j + 3];
            float v0 = __int_as_float(e0.y);
            float v1 = __int_as_float(e1.y);
            float v2 = __int_as_float(e2.y);
            float v3 = __int_as_float(e3.y);
            unsigned int u0 = xu[(size_t)e0.x * 64 + lane];
            unsigned int u1 = xu[(size_t)e1.x * 64 + lane];
            unsigned int u2 = xu[(size_t)e2.x * 64 + lane];
            unsigned int u3 = xu[(size_t)e3.x * 64 + lane];
            ax += v0 * bf_lo(u0) + v1 * bf_lo(u1) + v2 * bf_lo(u2) + v3 * bf_lo(u3);
            ay += v0 * bf_hi(u0) + v1 * bf_hi(u1) + v2 * bf_hi(u2) + v3 * bf_hi(u3);
            dg += v0 + v1 + v2 + v3;
        }
        for (; j < eN; ++j) {
            int2 e0 = csr[j];
            float v0 = __int_as_float(e0.y);
            unsigned int u0 = xu[(size_t)e0.x * 64 + lane];
            ax += v0 * bf_lo(u0);
            ay += v0 * bf_hi(u0);
            dg += v0;
        }
        float inv = 1.0f / (dg + 1e-6f);
        unsigned int o = ((unsigned int)f2bf(ay * inv) << 16) | f2bf(ax * inv);
        reinterpret_cast<unsigned int*>(h1h)[(size_t)node * 64 + lane] = o;
    }
}

// ---------------------------------------------------------------------------
// MFMA GEMM: out[N,128] = [xh | h1h] @ W (bf16 in, fp32 out).
// ---------------------------------------------------------------------------
__global__ __launch_bounds__(256) void gemm_kernel(
    const unsigned short* __restrict__ xh,
    const unsigned short* __restrict__ h1h,
    const unsigned short* __restrict__ wfrag,
    float* __restrict__ out)
{
    int l   = threadIdx.x & 63;
    int wid = threadIdx.x >> 6;
    int r0  = blockIdx.x * 64;
    int lr  = l & 15;
    int lk  = l >> 4;

    f32x4 acc[4][2];
    #pragma unroll
    for (int mf = 0; mf < 4; ++mf)
        #pragma unroll
        for (int nf = 0; nf < 2; ++nf)
            acc[mf][nf] = (f32x4){0.f, 0.f, 0.f, 0.f};

    #pragma unroll
    for (int ks = 0; ks < 8; ++ks) {
        const unsigned short* src = (ks < 4) ? xh : h1h;
        int coff = (ks & 3) * 32 + lk * 8;

        bf16x8 a[4];
        #pragma unroll
        for (int mf = 0; mf < 4; ++mf) {
            int row = r0 + mf * 16 + lr;
            if (row >= N_NODES) row = N_NODES - 1;
            a[mf] = *reinterpret_cast<const bf16x8*>(src + (size_t)row * DIM + coff);
        }
        bf16x8 bq[2];
        #pragma unroll
        for (int nf = 0; nf < 2; ++nf) {
            int nt = wid * 2 + nf;
            bq[nf] = *reinterpret_cast<const bf16x8*>(
                wfrag + ((size_t)((nt * 8 + ks) * 64 + l)) * 8);
        }
        #pragma unroll
        for (int mf = 0; mf < 4; ++mf)
            #pragma unroll
            for (int nf = 0; nf < 2; ++nf)
                acc[mf][nf] = __builtin_amdgcn_mfma_f32_16x16x32_bf16(
                    a[mf], bq[nf], acc[mf][nf], 0, 0, 0);
    }

    #pragma unroll
    for (int mf = 0; mf < 4; ++mf) {
        #pragma unroll
        for (int nf = 0; nf < 2; ++nf) {
            int col = wid * 32 + nf * 16 + lr;
            #pragma unroll
            for (int rr = 0; rr < 4; ++rr) {
                int row = r0 + mf * 16 + lk * 4 + rr;
                if (row < N_NODES)
                    out[(size_t)row * DIM + col] = acc[mf][nf][rr];
            }
        }
    }
}

extern "C" void kernel_launch(void* const* d_in, const int* in_sizes, int n_in,
                              void* d_out, int out_size, void* d_ws, size_t ws_size,
                              hipStream_t stream) {
    const float* x    = (const float*)d_in[0];
    const float* W    = (const float*)d_in[1];
    const int*   esrc = (const int*)d_in[2];
    const int*   edst = (const int*)d_in[3];
    const float* eval = (const float*)d_in[4];
    float* out = (float*)d_out;

    // ws layout (~34.8 MB; harness provides 256 MiB per poison-fill evidence):
    //   xh     : N*DIM bf16           (12.8 MB)
    //   h1h    : N*DIM bf16           (12.8 MB)
    //   queue  : NPART*QCAP int2      ( 9.0 MB)
    //   qcount : NPART ints           ( 4 KB)
    //   wfrag  : 32768 bf16           (64 KB)
    unsigned short* xh  = (unsigned short*)d_ws;
    unsigned short* h1h = xh + (size_t)N_NODES * DIM;
    int2* queue  = (int2*)(h1h + (size_t)N_NODES * DIM);
    int*  qcount = (int*)(queue + (size_t)NPART * QCAP);
    unsigned short* wfrag = (unsigned short*)(qcount + NPART);

    hipMemsetAsync(qcount, 0, NPART * sizeof(int), stream);
    fused_prep_kernel<<<BIN_TILES + XB + WCONV_B, 256, 0, stream>>>(
        x, xh, esrc, edst, eval, qcount, queue, W, wfrag);
    gather_local_kernel<<<NPART, 256, 0, stream>>>(xh, queue, qcount, h1h);
    gemm_kernel<<<(N_NODES + 63) / 64, 256, 0, stream>>>(xh, h1h, wfrag, out);
}

// Round 8
// 91.117 us; speedup vs baseline: 2.0167x; 1.1646x over previous
//
#include <hip/hip_runtime.h>
#include <hip/hip_bf16.h>

// GraphSage: h1 = segsum(val * x[dst] -> src) / deg; out = [x, h1norm] @ W
// N=50000, D=128, E=800000, W [256,128] fp32, out [N,128] fp32.
//
// Round-8 structure (zero global atomics anywhere):
//   k1 bincount : per-tile LDS histogram -> counts[tile][part]
//   k2 fused    : per-partition scan of counts (exact tile write bases)
//                 + x f32->bf16 convert + W MFMA-fragment pack
//   k3 place    : LDS cursors from scanned bases -> partition queues
//   k4 gather   : per-partition LDS CSR build + wave-per-node accumulation
//   k5 gemm     : bf16 MFMA, out = [xh | h1h] @ W

#define N_NODES 50000
#define DIM 128
#define N_EDGES 800000
#define NPART 1024      // partitions (49 nodes each)
#define PN 49
#define QCAP 1100       // per-partition queue cap (mean 781, ~+11 sigma)
#define BIN_T 4096      // edges per tile
#define T_TILES 196     // ceil(800000/4096) -> 196*4096 = 802816
#define XB 6250         // convert blocks (N*DIM/4/256)
#define WCONV_B 16

typedef __attribute__((ext_vector_type(8))) short bf16x8;
typedef __attribute__((ext_vector_type(4))) float f32x4;

__device__ __forceinline__ unsigned short f2bf(float f) {
    unsigned int u = __float_as_uint(f);
    unsigned int r = (u + 0x7FFFu + ((u >> 16) & 1u)) >> 16;
    return (unsigned short)r;
}
__device__ __forceinline__ float bf_lo(unsigned int u) {
    return __uint_as_float(u << 16);
}
__device__ __forceinline__ float bf_hi(unsigned int u) {
    return __uint_as_float(u & 0xFFFF0000u);
}

// ---------------------------------------------------------------------------
// k1: per-tile partition histogram. 196 blocks x 512 threads.
// ---------------------------------------------------------------------------
__global__ __launch_bounds__(512) void bincount_kernel(
    const int* __restrict__ esrc, int* __restrict__ counts)
{
    __shared__ int hist[NPART];
    int t = threadIdx.x;
    int b = blockIdx.x;

    #pragma unroll
    for (int i = t; i < NPART; i += 512) hist[i] = 0;
    __syncthreads();

    int e0 = b * BIN_T;
    #pragma unroll
    for (int i = t; i < BIN_T; i += 512) {
        int e = e0 + i;
        if (e < N_EDGES) {
            int P = esrc[e] / PN;
            atomicAdd(&hist[P], 1);
        }
    }
    __syncthreads();
    #pragma unroll
    for (int i = t; i < NPART; i += 512)
        counts[b * NPART + i] = hist[i];
}

// ---------------------------------------------------------------------------
// k2 fused: blocks [0,1024): per-partition exclusive scan across tiles
//           blocks [1024,1024+XB): x f32->bf16
//           blocks [1024+XB, ...): W pack into MFMA B-fragment order
// ---------------------------------------------------------------------------
__global__ __launch_bounds__(256) void scan_xconv_wconv_kernel(
    int* __restrict__ counts, int* __restrict__ qcount,
    const float* __restrict__ x, unsigned short* __restrict__ xh,
    const float* __restrict__ W, unsigned short* __restrict__ wfrag)
{
    int b = blockIdx.x;
    int t = threadIdx.x;

    if (b < NPART) {
        // exclusive scan of counts[0..T_TILES)[b] in-place; total -> qcount[b]
        __shared__ int s[256];
        int v = (t < T_TILES) ? counts[t * NPART + b] : 0;
        s[t] = v;
        __syncthreads();
        #pragma unroll
        for (int d = 1; d < 256; d <<= 1) {
            int tmp = (t >= d) ? s[t - d] : 0;
            __syncthreads();
            s[t] += tmp;
            __syncthreads();
        }
        if (t < T_TILES) counts[t * NPART + b] = s[t] - v;
        if (t == T_TILES - 1) qcount[b] = s[t];
        return;
    }

    if (b < NPART + XB) {
        int i = (b - NPART) * 256 + t;            // < 1,600,000 float4s
        float4 v = reinterpret_cast<const float4*>(x)[i];
        ushort4 o;
        o.x = f2bf(v.x); o.y = f2bf(v.y); o.z = f2bf(v.z); o.w = f2bf(v.w);
        reinterpret_cast<ushort4*>(xh)[i] = o;
        return;
    }

    {
        // Wfrag[((nt*8+ks)*64+l)*8+j] = bf16(W[ks*32+(l>>4)*8+j][nt*16+(l&15)])
        int idx = (b - NPART - XB) * 256 + t;     // 0..4095
        int l  = idx & 63;
        int ks = (idx >> 6) & 7;
        int nt = idx >> 9;
        int col  = nt * 16 + (l & 15);
        int krow = ks * 32 + (l >> 4) * 8;
        ushort4 lo, hi;
        lo.x = f2bf(W[(krow + 0) * DIM + col]);
        lo.y = f2bf(W[(krow + 1) * DIM + col]);
        lo.z = f2bf(W[(krow + 2) * DIM + col]);
        lo.w = f2bf(W[(krow + 3) * DIM + col]);
        hi.x = f2bf(W[(krow + 4) * DIM + col]);
        hi.y = f2bf(W[(krow + 5) * DIM + col]);
        hi.z = f2bf(W[(krow + 6) * DIM + col]);
        hi.w = f2bf(W[(krow + 7) * DIM + col]);
        reinterpret_cast<ushort4*>(wfrag)[idx * 2 + 0] = lo;
        reinterpret_cast<ushort4*>(wfrag)[idx * 2 + 1] = hi;
    }
}

// ---------------------------------------------------------------------------
// k3: place edges into partition queues using exact scanned bases.
// 196 blocks x 512 threads; only LDS atomics.
// ---------------------------------------------------------------------------
__global__ __launch_bounds__(512) void place_kernel(
    const int* __restrict__ esrc, const int* __restrict__ edst,
    const float* __restrict__ eval, const int* __restrict__ counts,
    int2* __restrict__ queue)
{
    __shared__ int cur[NPART];
    int t = threadIdx.x;
    int b = blockIdx.x;

    #pragma unroll
    for (int i = t; i < NPART; i += 512)
        cur[i] = counts[b * NPART + i];
    __syncthreads();

    int e0 = b * BIN_T;
    #pragma unroll
    for (int i = t; i < BIN_T; i += 512) {
        int e = e0 + i;
        if (e < N_EDGES) {
            int s = esrc[e];
            int P = s / PN;
            int ls = s - P * PN;                  // 0..48
            int pos = atomicAdd(&cur[P], 1);
            if (pos < QCAP) {
                int2 pk;
                pk.x = ls | (edst[e] << 6);       // 22 bits, positive
                pk.y = __float_as_int(eval[e]);
                queue[(size_t)P * QCAP + pos] = pk;
            }
        }
    }
}

// ---------------------------------------------------------------------------
// k4: gather with per-partition LDS CSR. One block per partition (49 nodes).
// ---------------------------------------------------------------------------
__global__ __launch_bounds__(256) void gather_local_kernel(
    const unsigned short* __restrict__ xh,
    const int2* __restrict__ queue, const int* __restrict__ qcount,
    unsigned short* __restrict__ h1h)
{
    __shared__ int cnt[64];
    __shared__ int off[64];
    __shared__ int cur[64];
    __shared__ int2 csr[QCAP];

    int b = blockIdx.x;
    int t = threadIdx.x;

    int n = qcount[b];
    if (n > QCAP) n = QCAP;
    const int2* q = queue + (size_t)b * QCAP;

    if (t < 64) cnt[t] = 0;
    __syncthreads();

    for (int i = t; i < n; i += 256) {
        int ls = q[i].x & 63;
        atomicAdd(&cnt[ls], 1);
    }
    __syncthreads();

    if (t < 64) off[t] = cnt[t];
    __syncthreads();
    #pragma unroll
    for (int d = 1; d < 64; d <<= 1) {
        int v = 0;
        if (t < 64 && t >= d) v = off[t - d];
        __syncthreads();
        if (t < 64) off[t] += v;
        __syncthreads();
    }
    if (t < 64) {
        int ex = off[t] - cnt[t];
        off[t] = ex;
        cur[t] = ex;
    }
    __syncthreads();

    for (int i = t; i < n; i += 256) {
        int2 e = q[i];
        int ls = e.x & 63;
        int pos = atomicAdd(&cur[ls], 1);
        int2 pk;
        pk.x = (int)(((unsigned int)e.x) >> 6);   // dst (unsigned shift)
        pk.y = e.y;
        csr[pos] = pk;
    }
    __syncthreads();

    int wid  = t >> 6;
    int lane = t & 63;
    const unsigned int* xu = reinterpret_cast<const unsigned int*>(xh);

    for (int ls = wid; ls < PN; ls += 4) {
        int node = b * PN + ls;
        if (node >= N_NODES) break;
        int s  = off[ls];
        int eN = s + cnt[ls];

        float ax = 0.0f, ay = 0.0f, dg = 0.0f;
        int j = s;
        for (; j + 3 < eN; j += 4) {
            int2 e0 = csr[j];
            int2 e1 = csr[j + 1];
            int2 e2 = csr[j + 2];
            int2 e3 = csr[j + 3];
            float v0 = __int_as_float(e0.y);
            float v1 = __int_as_float(e1.y);
            float v2 = __int_as_float(e2.y);
            float v3 = __int_as_float(e3.y);
            unsigned int u0 = xu[(size_t)e0.x * 64 + lane];
            unsigned int u1 = xu[(size_t)e1.x * 64 + lane];
            unsigned int u2 = xu[(size_t)e2.x * 64 + lane];
            unsigned int u3 = xu[(size_t)e3.x * 64 + lane];
            ax += v0 * bf_lo(u0) + v1 * bf_lo(u1) + v2 * bf_lo(u2) + v3 * bf_lo(u3);
            ay += v0 * bf_hi(u0) + v1 * bf_hi(u1) + v2 * bf_hi(u2) + v3 * bf_hi(u3);
            dg += v0 + v1 + v2 + v3;
        }
        for (; j < eN; ++j) {
            int2 e0 = csr[j];
            float v0 = __int_as_float(e0.y);
            unsigned int u0 = xu[(size_t)e0.x * 64 + lane];
            ax += v0 * bf_lo(u0);
            ay += v0 * bf_hi(u0);
            dg += v0;
        }
        float inv = 1.0f / (dg + 1e-6f);
        unsigned int o = ((unsigned int)f2bf(ay * inv) << 16) | f2bf(ax * inv);
        reinterpret_cast<unsigned int*>(h1h)[(size_t)node * 64 + lane] = o;
    }
}

// ---------------------------------------------------------------------------
// k5: MFMA GEMM, out[N,128] = [xh | h1h] @ W (bf16 in, fp32 out).
// ---------------------------------------------------------------------------
__global__ __launch_bounds__(256) void gemm_kernel(
    const unsigned short* __restrict__ xh,
    const unsigned short* __restrict__ h1h,
    const unsigned short* __restrict__ wfrag,
    float* __restrict__ out)
{
    int l   = threadIdx.x & 63;
    int wid = threadIdx.x >> 6;
    int r0  = blockIdx.x * 64;
    int lr  = l & 15;
    int lk  = l >> 4;

    f32x4 acc[4][2];
    #pragma unroll
    for (int mf = 0; mf < 4; ++mf)
        #pragma unroll
        for (int nf = 0; nf < 2; ++nf)
            acc[mf][nf] = (f32x4){0.f, 0.f, 0.f, 0.f};

    #pragma unroll
    for (int ks = 0; ks < 8; ++ks) {
        const unsigned short* src = (ks < 4) ? xh : h1h;
        int coff = (ks & 3) * 32 + lk * 8;

        bf16x8 a[4];
        #pragma unroll
        for (int mf = 0; mf < 4; ++mf) {
            int row = r0 + mf * 16 + lr;
            if (row >= N_NODES) row = N_NODES - 1;
            a[mf] = *reinterpret_cast<const bf16x8*>(src + (size_t)row * DIM + coff);
        }
        bf16x8 bq[2];
        #pragma unroll
        for (int nf = 0; nf < 2; ++nf) {
            int nt = wid * 2 + nf;
            bq[nf] = *reinterpret_cast<const bf16x8*>(
                wfrag + ((size_t)((nt * 8 + ks) * 64 + l)) * 8);
        }
        #pragma unroll
        for (int mf = 0; mf < 4; ++mf)
            #pragma unroll
            for (int nf = 0; nf < 2; ++nf)
                acc[mf][nf] = __builtin_amdgcn_mfma_f32_16x16x32_bf16(
                    a[mf], bq[nf], acc[mf][nf], 0, 0, 0);
    }

    #pragma unroll
    for (int mf = 0; mf < 4; ++mf) {
        #pragma unroll
        for (int nf = 0; nf < 2; ++nf) {
            int col = wid * 32 + nf * 16 + lr;
            #pragma unroll
            for (int rr = 0; rr < 4; ++rr) {
                int row = r0 + mf * 16 + lk * 4 + rr;
                if (row < N_NODES)
                    out[(size_t)row * DIM + col] = acc[mf][nf][rr];
            }
        }
    }
}

extern "C" void kernel_launch(void* const* d_in, const int* in_sizes, int n_in,
                              void* d_out, int out_size, void* d_ws, size_t ws_size,
                              hipStream_t stream) {
    const float* x    = (const float*)d_in[0];
    const float* W    = (const float*)d_in[1];
    const int*   esrc = (const int*)d_in[2];
    const int*   edst = (const int*)d_in[3];
    const float* eval = (const float*)d_in[4];
    float* out = (float*)d_out;

    // ws layout (~35.5 MB; harness ws is 256 MiB per poison-fill evidence):
    //   xh     : N*DIM bf16            (12.8 MB)
    //   h1h    : N*DIM bf16            (12.8 MB)
    //   queue  : NPART*QCAP int2       ( 9.0 MB)
    //   counts : T_TILES*NPART ints    ( 0.8 MB)
    //   qcount : NPART ints            ( 4 KB)
    //   wfrag  : 32768 bf16            (64 KB)
    unsigned short* xh  = (unsigned short*)d_ws;
    unsigned short* h1h = xh + (size_t)N_NODES * DIM;
    int2* queue  = (int2*)(h1h + (size_t)N_NODES * DIM);
    int*  counts = (int*)(queue + (size_t)NPART * QCAP);
    int*  qcount = counts + (size_t)T_TILES * NPART;
    unsigned short* wfrag = (unsigned short*)(qcount + NPART);

    bincount_kernel<<<T_TILES, 512, 0, stream>>>(esrc, counts);
    scan_xconv_wconv_kernel<<<NPART + XB + WCONV_B, 256, 0, stream>>>(
        counts, qcount, x, xh, W, wfrag);
    place_kernel<<<T_TILES, 512, 0, stream>>>(esrc, edst, eval, counts, queue);
    gather_local_kernel<<<NPART, 256, 0, stream>>>(xh, queue, qcount, h1h);
    gemm_kernel<<<(N_NODES + 63) / 64, 256, 0, stream>>>(xh, h1h, wfrag, out);
}

// Round 9
// 81.856 us; speedup vs baseline: 2.2449x; 1.1131x over previous
//
#include <hip/hip_runtime.h>
#include <hip/hip_bf16.h>

// GraphSage: h1 = segsum(val * x[dst] -> src) / deg; out = [x, h1norm] @ W
// N=50000, D=128, E=800000, W [256,128] fp32, out [N,128] fp32.
//
// Round-9 structure:
//   k1 bincount : per-tile LDS histogram -> counts[tile][part]
//   k2 fused    : per-partition scan (exact tile write bases) + x f32->bf16
//                 + W MFMA-fragment pack
//   k3 place    : LDS cursors -> partition queues (only LDS atomics)
//   k4 gather_gemm : per-partition LDS CSR + 8-wave gather into swizzled LDS
//                 h1 tile + fused 64-row MFMA GEMM -> out (no h1h round-trip)

#define N_NODES 50000
#define DIM 128
#define N_EDGES 800000
#define NPART 784       // partitions of PN=64 nodes (784*64 = 50176)
#define PN 64
#define QCAP 1408       // per-partition cap (mean 1020, +12 sigma)
#define BIN_T 4096
#define T_TILES 196     // ceil(800000/4096)
#define XB 6250         // convert blocks (N*DIM/4/256)
#define WCONV_B 16

typedef __attribute__((ext_vector_type(8))) short bf16x8;
typedef __attribute__((ext_vector_type(4))) float f32x4;

__device__ __forceinline__ unsigned short f2bf(float f) {
    unsigned int u = __float_as_uint(f);
    unsigned int r = (u + 0x7FFFu + ((u >> 16) & 1u)) >> 16;
    return (unsigned short)r;
}
__device__ __forceinline__ float bf_lo(unsigned int u) {
    return __uint_as_float(u << 16);
}
__device__ __forceinline__ float bf_hi(unsigned int u) {
    return __uint_as_float(u & 0xFFFF0000u);
}

// ---------------------------------------------------------------------------
// k1: per-tile partition histogram. 196 blocks x 512 threads.
// ---------------------------------------------------------------------------
__global__ __launch_bounds__(512) void bincount_kernel(
    const int* __restrict__ esrc, int* __restrict__ counts)
{
    __shared__ int hist[NPART];
    int t = threadIdx.x;
    int b = blockIdx.x;

    for (int i = t; i < NPART; i += 512) hist[i] = 0;
    __syncthreads();

    int e0 = b * BIN_T;
    #pragma unroll
    for (int i = t; i < BIN_T; i += 512) {
        int e = e0 + i;
        if (e < N_EDGES) {
            int P = esrc[e] >> 6;          // PN = 64
            atomicAdd(&hist[P], 1);
        }
    }
    __syncthreads();
    for (int i = t; i < NPART; i += 512)
        counts[b * NPART + i] = hist[i];
}

// ---------------------------------------------------------------------------
// k2 fused: blocks [0,NPART): per-partition exclusive scan across tiles
//           blocks [NPART,NPART+XB): x f32->bf16
//           blocks [NPART+XB,...): W pack into MFMA B-fragment order
// ---------------------------------------------------------------------------
__global__ __launch_bounds__(256) void scan_xconv_wconv_kernel(
    int* __restrict__ counts, int* __restrict__ qcount,
    const float* __restrict__ x, unsigned short* __restrict__ xh,
    const float* __restrict__ W, unsigned short* __restrict__ wfrag)
{
    int b = blockIdx.x;
    int t = threadIdx.x;

    if (b < NPART) {
        __shared__ int s[256];
        int v = (t < T_TILES) ? counts[t * NPART + b] : 0;
        s[t] = v;
        __syncthreads();
        #pragma unroll
        for (int d = 1; d < 256; d <<= 1) {
            int tmp = (t >= d) ? s[t - d] : 0;
            __syncthreads();
            s[t] += tmp;
            __syncthreads();
        }
        if (t < T_TILES) counts[t * NPART + b] = s[t] - v;
        if (t == T_TILES - 1) qcount[b] = s[t];
        return;
    }

    if (b < NPART + XB) {
        int i = (b - NPART) * 256 + t;            // < 1,600,000 float4s
        float4 v = reinterpret_cast<const float4*>(x)[i];
        ushort4 o;
        o.x = f2bf(v.x); o.y = f2bf(v.y); o.z = f2bf(v.z); o.w = f2bf(v.w);
        reinterpret_cast<ushort4*>(xh)[i] = o;
        return;
    }

    {
        // Wfrag[((nt*8+ks)*64+l)*8+j] = bf16(W[ks*32+(l>>4)*8+j][nt*16+(l&15)])
        int idx = (b - NPART - XB) * 256 + t;     // 0..4095
        int l  = idx & 63;
        int ks = (idx >> 6) & 7;
        int nt = idx >> 9;
        int col  = nt * 16 + (l & 15);
        int krow = ks * 32 + (l >> 4) * 8;
        ushort4 lo, hi;
        lo.x = f2bf(W[(krow + 0) * DIM + col]);
        lo.y = f2bf(W[(krow + 1) * DIM + col]);
        lo.z = f2bf(W[(krow + 2) * DIM + col]);
        lo.w = f2bf(W[(krow + 3) * DIM + col]);
        hi.x = f2bf(W[(krow + 4) * DIM + col]);
        hi.y = f2bf(W[(krow + 5) * DIM + col]);
        hi.z = f2bf(W[(krow + 6) * DIM + col]);
        hi.w = f2bf(W[(krow + 7) * DIM + col]);
        reinterpret_cast<ushort4*>(wfrag)[idx * 2 + 0] = lo;
        reinterpret_cast<ushort4*>(wfrag)[idx * 2 + 1] = hi;
    }
}

// ---------------------------------------------------------------------------
// k3: place edges into partition queues using exact scanned bases.
// ---------------------------------------------------------------------------
__global__ __launch_bounds__(512) void place_kernel(
    const int* __restrict__ esrc, const int* __restrict__ edst,
    const float* __restrict__ eval, const int* __restrict__ counts,
    int2* __restrict__ queue)
{
    __shared__ int cur[NPART];
    int t = threadIdx.x;
    int b = blockIdx.x;

    for (int i = t; i < NPART; i += 512)
        cur[i] = counts[b * NPART + i];
    __syncthreads();

    int e0 = b * BIN_T;
    #pragma unroll
    for (int i = t; i < BIN_T; i += 512) {
        int e = e0 + i;
        if (e < N_EDGES) {
            int s = esrc[e];
            int P = s >> 6;
            int ls = s & 63;
            int pos = atomicAdd(&cur[P], 1);
            if (pos < QCAP) {
                int2 pk;
                pk.x = ls | (edst[e] << 6);       // < 2^22, positive
                pk.y = __float_as_int(eval[e]);
                queue[(size_t)P * QCAP + pos] = pk;
            }
        }
    }
}

// ---------------------------------------------------------------------------
// k4: fused gather + GEMM. One 512-thread block per partition (64 nodes).
// Phase A: build per-partition CSR in LDS.
// Phase B: 8 waves gather rows (8-deep unroll) -> swizzled LDS h1 tile.
// Phase C: 64-row MFMA GEMM: out = [xh | h1] @ W.
// LDS: csr 11264 + h1s 16384 + 768 = 28416 B -> ~5 blocks/CU possible.
// ---------------------------------------------------------------------------
__global__ __launch_bounds__(512) void gather_gemm_kernel(
    const unsigned short* __restrict__ xh,
    const int2* __restrict__ queue, const int* __restrict__ qcount,
    const unsigned short* __restrict__ wfrag,
    float* __restrict__ out)
{
    __shared__ int cnt[64];
    __shared__ int off[64];
    __shared__ int cur[64];
    __shared__ int2 csr[QCAP];
    __shared__ unsigned int h1s[64 * 64];   // row-major uint (2 bf16), swizzled

    int b = blockIdx.x;
    int t = threadIdx.x;

    int n = qcount[b];
    if (n > QCAP) n = QCAP;
    const int2* q = queue + (size_t)b * QCAP;

    // ---- Phase A: LDS CSR ----
    if (t < 64) cnt[t] = 0;
    __syncthreads();
    for (int i = t; i < n; i += 512)
        atomicAdd(&cnt[q[i].x & 63], 1);
    __syncthreads();
    if (t < 64) off[t] = cnt[t];
    __syncthreads();
    #pragma unroll
    for (int d = 1; d < 64; d <<= 1) {
        int v = 0;
        if (t < 64 && t >= d) v = off[t - d];
        __syncthreads();
        if (t < 64) off[t] += v;
        __syncthreads();
    }
    if (t < 64) { int ex = off[t] - cnt[t]; off[t] = ex; cur[t] = ex; }
    __syncthreads();
    for (int i = t; i < n; i += 512) {
        int2 e = q[i];
        int ls = e.x & 63;
        int pos = atomicAdd(&cur[ls], 1);
        int2 pk;
        pk.x = (int)(((unsigned int)e.x) >> 6);   // dst (unsigned shift)
        pk.y = e.y;
        csr[pos] = pk;
    }
    __syncthreads();

    // ---- Phase B: gather. Wave w handles local nodes w, w+8, ... ----
    int wid  = t >> 6;
    int lane = t & 63;
    const unsigned int* xu = reinterpret_cast<const unsigned int*>(xh);

    for (int ls = wid; ls < PN; ls += 8) {
        int node = b * PN + ls;
        if (node >= N_NODES) break;
        int s  = off[ls];
        int eN = s + cnt[ls];

        float ax = 0.0f, ay = 0.0f, dg = 0.0f;
        int j = s;
        for (; j + 7 < eN; j += 8) {
            int2 e0 = csr[j + 0]; int2 e1 = csr[j + 1];
            int2 e2 = csr[j + 2]; int2 e3 = csr[j + 3];
            int2 e4 = csr[j + 4]; int2 e5 = csr[j + 5];
            int2 e6 = csr[j + 6]; int2 e7 = csr[j + 7];
            unsigned int u0 = xu[(size_t)e0.x * 64 + lane];
            unsigned int u1 = xu[(size_t)e1.x * 64 + lane];
            unsigned int u2 = xu[(size_t)e2.x * 64 + lane];
            unsigned int u3 = xu[(size_t)e3.x * 64 + lane];
            unsigned int u4 = xu[(size_t)e4.x * 64 + lane];
            unsigned int u5 = xu[(size_t)e5.x * 64 + lane];
            unsigned int u6 = xu[(size_t)e6.x * 64 + lane];
            unsigned int u7 = xu[(size_t)e7.x * 64 + lane];
            float v0 = __int_as_float(e0.y); float v1 = __int_as_float(e1.y);
            float v2 = __int_as_float(e2.y); float v3 = __int_as_float(e3.y);
            float v4 = __int_as_float(e4.y); float v5 = __int_as_float(e5.y);
            float v6 = __int_as_float(e6.y); float v7 = __int_as_float(e7.y);
            ax += v0 * bf_lo(u0) + v1 * bf_lo(u1) + v2 * bf_lo(u2) + v3 * bf_lo(u3);
            ax += v4 * bf_lo(u4) + v5 * bf_lo(u5) + v6 * bf_lo(u6) + v7 * bf_lo(u7);
            ay += v0 * bf_hi(u0) + v1 * bf_hi(u1) + v2 * bf_hi(u2) + v3 * bf_hi(u3);
            ay += v4 * bf_hi(u4) + v5 * bf_hi(u5) + v6 * bf_hi(u6) + v7 * bf_hi(u7);
            dg += v0 + v1 + v2 + v3 + v4 + v5 + v6 + v7;
        }
        for (; j < eN; ++j) {
            int2 e0 = csr[j];
            float v0 = __int_as_float(e0.y);
            unsigned int u0 = xu[(size_t)e0.x * 64 + lane];
            ax += v0 * bf_lo(u0);
            ay += v0 * bf_hi(u0);
            dg += v0;
        }
        float inv = 1.0f / (dg + 1e-6f);
        unsigned int o = ((unsigned int)f2bf(ay * inv) << 16) | f2bf(ax * inv);
        // swizzled store: uint col = lane, physical idx ^= (row&7)<<2
        h1s[ls * 64 + (lane ^ ((ls & 7) << 2))] = o;
    }
    __syncthreads();

    // ---- Phase C: GEMM. Wave wid covers cols [wid*16, wid*16+16). ----
    int lr = lane & 15;
    int lk = lane >> 4;
    int r0 = b * PN;

    f32x4 acc[4];
    #pragma unroll
    for (int mf = 0; mf < 4; ++mf) acc[mf] = (f32x4){0.f, 0.f, 0.f, 0.f};

    #pragma unroll
    for (int ks = 0; ks < 8; ++ks) {
        bf16x8 a[4];
        if (ks < 4) {
            int coff = ks * 32 + lk * 8;
            #pragma unroll
            for (int mf = 0; mf < 4; ++mf) {
                int row = r0 + mf * 16 + lr;
                if (row >= N_NODES) row = N_NODES - 1;
                a[mf] = *reinterpret_cast<const bf16x8*>(
                    xh + (size_t)row * DIM + coff);
            }
        } else {
            int ucoff = (ks - 4) * 16 + lk * 4;
            #pragma unroll
            for (int mf = 0; mf < 4; ++mf) {
                int row = mf * 16 + lr;
                a[mf] = *reinterpret_cast<const bf16x8*>(
                    &h1s[row * 64 + (ucoff ^ ((row & 7) << 2))]);
            }
        }
        bf16x8 bq = *reinterpret_cast<const bf16x8*>(
            wfrag + ((size_t)((wid * 8 + ks) * 64 + lane)) * 8);
        #pragma unroll
        for (int mf = 0; mf < 4; ++mf)
            acc[mf] = __builtin_amdgcn_mfma_f32_16x16x32_bf16(
                a[mf], bq, acc[mf], 0, 0, 0);
    }

    #pragma unroll
    for (int mf = 0; mf < 4; ++mf) {
        int col = wid * 16 + lr;
        #pragma unroll
        for (int rr = 0; rr < 4; ++rr) {
            int row = r0 + mf * 16 + lk * 4 + rr;
            if (row < N_NODES)
                out[(size_t)row * DIM + col] = acc[mf][rr];
        }
    }
}

extern "C" void kernel_launch(void* const* d_in, const int* in_sizes, int n_in,
                              void* d_out, int out_size, void* d_ws, size_t ws_size,
                              hipStream_t stream) {
    const float* x    = (const float*)d_in[0];
    const float* W    = (const float*)d_in[1];
    const int*   esrc = (const int*)d_in[2];
    const int*   edst = (const int*)d_in[3];
    const float* eval = (const float*)d_in[4];
    float* out = (float*)d_out;

    // ws layout (~22.3 MB):
    //   xh     : N*DIM bf16            (12.8 MB)
    //   queue  : NPART*QCAP int2       ( 8.8 MB)
    //   counts : T_TILES*NPART ints    ( 0.6 MB)
    //   qcount : NPART ints            ( 3 KB)
    //   wfrag  : 32768 bf16            (64 KB)
    unsigned short* xh  = (unsigned short*)d_ws;
    int2* queue  = (int2*)(xh + (size_t)N_NODES * DIM);
    int*  counts = (int*)(queue + (size_t)NPART * QCAP);
    int*  qcount = counts + (size_t)T_TILES * NPART;
    unsigned short* wfrag = (unsigned short*)(qcount + NPART);

    bincount_kernel<<<T_TILES, 512, 0, stream>>>(esrc, counts);
    scan_xconv_wconv_kernel<<<NPART + XB + WCONV_B, 256, 0, stream>>>(
        counts, qcount, x, xh, W, wfrag);
    place_kernel<<<T_TILES, 512, 0, stream>>>(esrc, edst, eval, counts, queue);
    gather_gemm_kernel<<<NPART, 512, 0, stream>>>(xh, queue, qcount, wfrag, out);
}

// Round 10
// 80.324 us; speedup vs baseline: 2.2877x; 1.0191x over previous
//
#include <hip/hip_runtime.h>
#include <hip/hip_bf16.h>

// GraphSage: h1 = segsum(val * x[dst] -> src) / deg; out = [x, h1norm] @ W
// N=50000, D=128, E=800000, W [256,128] fp32, out [N,128] fp32.
//
// Round-10 structure:
//   k1 bincount : per-tile LDS histogram -> counts[tile][part]
//   k2 fused    : per-partition scan (exact tile write bases) + x f32->bf16
//                 + W MFMA-fragment pack
//   k3 place    : LDS cursors -> partition queues (only LDS atomics)
//   k4 gather_gemm : per-partition (32 nodes) LDS CSR + 8-wave gather into
//                 swizzled LDS h1 tile + fused 32-row MFMA GEMM -> out
//   PN=32/NPART=1568 for occupancy (r9 was 784 blocks = 3/CU, Occ 42%).

#define N_NODES 50000
#define DIM 128
#define N_EDGES 800000
#define NPART 1568      // partitions of PN=32 nodes (1568*32 = 50176)
#define PN 32
#define QCAP 768        // per-partition cap (mean 510, ~+11 sigma)
#define BIN_T 4096
#define T_TILES 196     // ceil(800000/4096)
#define XB 6250         // convert blocks (N*DIM/4/256)
#define WCONV_B 16

typedef __attribute__((ext_vector_type(8))) short bf16x8;
typedef __attribute__((ext_vector_type(4))) float f32x4;

__device__ __forceinline__ unsigned short f2bf(float f) {
    unsigned int u = __float_as_uint(f);
    unsigned int r = (u + 0x7FFFu + ((u >> 16) & 1u)) >> 16;
    return (unsigned short)r;
}
__device__ __forceinline__ float bf_lo(unsigned int u) {
    return __uint_as_float(u << 16);
}
__device__ __forceinline__ float bf_hi(unsigned int u) {
    return __uint_as_float(u & 0xFFFF0000u);
}

// ---------------------------------------------------------------------------
// k1: per-tile partition histogram. 196 blocks x 512 threads.
// ---------------------------------------------------------------------------
__global__ __launch_bounds__(512) void bincount_kernel(
    const int* __restrict__ esrc, int* __restrict__ counts)
{
    __shared__ int hist[NPART];
    int t = threadIdx.x;
    int b = blockIdx.x;

    for (int i = t; i < NPART; i += 512) hist[i] = 0;
    __syncthreads();

    int e0 = b * BIN_T;
    #pragma unroll
    for (int i = t; i < BIN_T; i += 512) {
        int e = e0 + i;
        if (e < N_EDGES) {
            int P = esrc[e] >> 5;          // PN = 32
            atomicAdd(&hist[P], 1);
        }
    }
    __syncthreads();
    for (int i = t; i < NPART; i += 512)
        counts[b * NPART + i] = hist[i];
}

// ---------------------------------------------------------------------------
// k2 fused: blocks [0,NPART): per-partition exclusive scan across tiles
//           blocks [NPART,NPART+XB): x f32->bf16
//           blocks [NPART+XB,...): W pack into MFMA B-fragment order
// ---------------------------------------------------------------------------
__global__ __launch_bounds__(256) void scan_xconv_wconv_kernel(
    int* __restrict__ counts, int* __restrict__ qcount,
    const float* __restrict__ x, unsigned short* __restrict__ xh,
    const float* __restrict__ W, unsigned short* __restrict__ wfrag)
{
    int b = blockIdx.x;
    int t = threadIdx.x;

    if (b < NPART) {
        __shared__ int s[256];
        int v = (t < T_TILES) ? counts[t * NPART + b] : 0;
        s[t] = v;
        __syncthreads();
        #pragma unroll
        for (int d = 1; d < 256; d <<= 1) {
            int tmp = (t >= d) ? s[t - d] : 0;
            __syncthreads();
            s[t] += tmp;
            __syncthreads();
        }
        if (t < T_TILES) counts[t * NPART + b] = s[t] - v;
        if (t == T_TILES - 1) qcount[b] = s[t];
        return;
    }

    if (b < NPART + XB) {
        int i = (b - NPART) * 256 + t;            // < 1,600,000 float4s
        float4 v = reinterpret_cast<const float4*>(x)[i];
        ushort4 o;
        o.x = f2bf(v.x); o.y = f2bf(v.y); o.z = f2bf(v.z); o.w = f2bf(v.w);
        reinterpret_cast<ushort4*>(xh)[i] = o;
        return;
    }

    {
        // Wfrag[((nt*8+ks)*64+l)*8+j] = bf16(W[ks*32+(l>>4)*8+j][nt*16+(l&15)])
        int idx = (b - NPART - XB) * 256 + t;     // 0..4095
        int l  = idx & 63;
        int ks = (idx >> 6) & 7;
        int nt = idx >> 9;
        int col  = nt * 16 + (l & 15);
        int krow = ks * 32 + (l >> 4) * 8;
        ushort4 lo, hi;
        lo.x = f2bf(W[(krow + 0) * DIM + col]);
        lo.y = f2bf(W[(krow + 1) * DIM + col]);
        lo.z = f2bf(W[(krow + 2) * DIM + col]);
        lo.w = f2bf(W[(krow + 3) * DIM + col]);
        hi.x = f2bf(W[(krow + 4) * DIM + col]);
        hi.y = f2bf(W[(krow + 5) * DIM + col]);
        hi.z = f2bf(W[(krow + 6) * DIM + col]);
        hi.w = f2bf(W[(krow + 7) * DIM + col]);
        reinterpret_cast<ushort4*>(wfrag)[idx * 2 + 0] = lo;
        reinterpret_cast<ushort4*>(wfrag)[idx * 2 + 1] = hi;
    }
}

// ---------------------------------------------------------------------------
// k3: place edges into partition queues using exact scanned bases.
// ---------------------------------------------------------------------------
__global__ __launch_bounds__(512) void place_kernel(
    const int* __restrict__ esrc, const int* __restrict__ edst,
    const float* __restrict__ eval, const int* __restrict__ counts,
    int2* __restrict__ queue)
{
    __shared__ int cur[NPART];
    int t = threadIdx.x;
    int b = blockIdx.x;

    for (int i = t; i < NPART; i += 512)
        cur[i] = counts[b * NPART + i];
    __syncthreads();

    int e0 = b * BIN_T;
    #pragma unroll
    for (int i = t; i < BIN_T; i += 512) {
        int e = e0 + i;
        if (e < N_EDGES) {
            int s = esrc[e];
            int P = s >> 5;
            int ls = s & 31;
            int pos = atomicAdd(&cur[P], 1);
            if (pos < QCAP) {
                int2 pk;
                pk.x = ls | (edst[e] << 5);       // < 2^21, positive
                pk.y = __float_as_int(eval[e]);
                queue[(size_t)P * QCAP + pos] = pk;
            }
        }
    }
}

// ---------------------------------------------------------------------------
// k4: fused gather + GEMM. One 512-thread block per partition (32 nodes).
// Phase A: build per-partition CSR in LDS.
// Phase B: 8 waves gather rows (8/4-deep unroll, split acc chains) ->
//          swizzled LDS h1 tile (uint[32][64]).
// Phase C: 32-row MFMA GEMM: out = [xh | h1] @ W.
// LDS: csr 6144 + h1s 8192 + 384 = ~14.7 KB -> 4 blocks/CU (wave-capped).
// ---------------------------------------------------------------------------
__global__ __launch_bounds__(512) void gather_gemm_kernel(
    const unsigned short* __restrict__ xh,
    const int2* __restrict__ queue, const int* __restrict__ qcount,
    const unsigned short* __restrict__ wfrag,
    float* __restrict__ out)
{
    __shared__ int cnt[PN];
    __shared__ int off[PN];
    __shared__ int cur[PN];
    __shared__ int2 csr[QCAP];
    __shared__ unsigned int h1s[PN * 64];   // row-major uint (2 bf16), swizzled

    int b = blockIdx.x;
    int t = threadIdx.x;

    int n = qcount[b];
    if (n > QCAP) n = QCAP;
    const int2* q = queue + (size_t)b * QCAP;

    // ---- Phase A: LDS CSR ----
    if (t < PN) cnt[t] = 0;
    __syncthreads();
    for (int i = t; i < n; i += 512)
        atomicAdd(&cnt[q[i].x & 31], 1);
    __syncthreads();
    if (t < PN) off[t] = cnt[t];
    __syncthreads();
    #pragma unroll
    for (int d = 1; d < PN; d <<= 1) {
        int v = 0;
        if (t < PN && t >= d) v = off[t - d];
        __syncthreads();
        if (t < PN) off[t] += v;
        __syncthreads();
    }
    if (t < PN) { int ex = off[t] - cnt[t]; off[t] = ex; cur[t] = ex; }
    __syncthreads();
    for (int i = t; i < n; i += 512) {
        int2 e = q[i];
        int ls = e.x & 31;
        int pos = atomicAdd(&cur[ls], 1);
        int2 pk;
        pk.x = (int)(((unsigned int)e.x) >> 5);   // dst (unsigned shift)
        pk.y = e.y;
        csr[pos] = pk;
    }
    __syncthreads();

    // ---- Phase B: gather. Wave w handles local nodes w, w+8, w+16, w+24 ----
    int wid  = t >> 6;
    int lane = t & 63;
    const unsigned int* xu = reinterpret_cast<const unsigned int*>(xh);

    for (int ls = wid; ls < PN; ls += 8) {
        int node = b * PN + ls;
        if (node >= N_NODES) break;
        int s  = off[ls];
        int eN = s + cnt[ls];

        float ax0 = 0.f, ax1 = 0.f, ay0 = 0.f, ay1 = 0.f, dg0 = 0.f, dg1 = 0.f;
        int j = s;
        for (; j + 7 < eN; j += 8) {
            int2 e0 = csr[j + 0]; int2 e1 = csr[j + 1];
            int2 e2 = csr[j + 2]; int2 e3 = csr[j + 3];
            int2 e4 = csr[j + 4]; int2 e5 = csr[j + 5];
            int2 e6 = csr[j + 6]; int2 e7 = csr[j + 7];
            unsigned int u0 = xu[(size_t)e0.x * 64 + lane];
            unsigned int u1 = xu[(size_t)e1.x * 64 + lane];
            unsigned int u2 = xu[(size_t)e2.x * 64 + lane];
            unsigned int u3 = xu[(size_t)e3.x * 64 + lane];
            unsigned int u4 = xu[(size_t)e4.x * 64 + lane];
            unsigned int u5 = xu[(size_t)e5.x * 64 + lane];
            unsigned int u6 = xu[(size_t)e6.x * 64 + lane];
            unsigned int u7 = xu[(size_t)e7.x * 64 + lane];
            float v0 = __int_as_float(e0.y); float v1 = __int_as_float(e1.y);
            float v2 = __int_as_float(e2.y); float v3 = __int_as_float(e3.y);
            float v4 = __int_as_float(e4.y); float v5 = __int_as_float(e5.y);
            float v6 = __int_as_float(e6.y); float v7 = __int_as_float(e7.y);
            ax0 += v0 * bf_lo(u0) + v1 * bf_lo(u1) + v2 * bf_lo(u2) + v3 * bf_lo(u3);
            ax1 += v4 * bf_lo(u4) + v5 * bf_lo(u5) + v6 * bf_lo(u6) + v7 * bf_lo(u7);
            ay0 += v0 * bf_hi(u0) + v1 * bf_hi(u1) + v2 * bf_hi(u2) + v3 * bf_hi(u3);
            ay1 += v4 * bf_hi(u4) + v5 * bf_hi(u5) + v6 * bf_hi(u6) + v7 * bf_hi(u7);
            dg0 += v0 + v1 + v2 + v3;
            dg1 += v4 + v5 + v6 + v7;
        }
        if (j + 3 < eN) {
            int2 e0 = csr[j + 0]; int2 e1 = csr[j + 1];
            int2 e2 = csr[j + 2]; int2 e3 = csr[j + 3];
            unsigned int u0 = xu[(size_t)e0.x * 64 + lane];
            unsigned int u1 = xu[(size_t)e1.x * 64 + lane];
            unsigned int u2 = xu[(size_t)e2.x * 64 + lane];
            unsigned int u3 = xu[(size_t)e3.x * 64 + lane];
            float v0 = __int_as_float(e0.y); float v1 = __int_as_float(e1.y);
            float v2 = __int_as_float(e2.y); float v3 = __int_as_float(e3.y);
            ax0 += v0 * bf_lo(u0) + v1 * bf_lo(u1);
            ax1 += v2 * bf_lo(u2) + v3 * bf_lo(u3);
            ay0 += v0 * bf_hi(u0) + v1 * bf_hi(u1);
            ay1 += v2 * bf_hi(u2) + v3 * bf_hi(u3);
            dg0 += v0 + v1;
            dg1 += v2 + v3;
            j += 4;
        }
        for (; j < eN; ++j) {
            int2 e0 = csr[j];
            float v0 = __int_as_float(e0.y);
            unsigned int u0 = xu[(size_t)e0.x * 64 + lane];
            ax0 += v0 * bf_lo(u0);
            ay0 += v0 * bf_hi(u0);
            dg0 += v0;
        }
        float dg = dg0 + dg1;
        float inv = 1.0f / (dg + 1e-6f);
        float ax = ax0 + ax1, ay = ay0 + ay1;
        unsigned int o = ((unsigned int)f2bf(ay * inv) << 16) | f2bf(ax * inv);
        // swizzled store: uint col = lane, physical idx ^= (row&7)<<2
        h1s[ls * 64 + (lane ^ ((ls & 7) << 2))] = o;
    }
    __syncthreads();

    // ---- Phase C: GEMM. Wave wid covers cols [wid*16, wid*16+16). ----
    int lr = lane & 15;
    int lk = lane >> 4;
    int r0 = b * PN;

    f32x4 acc[2];
    #pragma unroll
    for (int mf = 0; mf < 2; ++mf) acc[mf] = (f32x4){0.f, 0.f, 0.f, 0.f};

    #pragma unroll
    for (int ks = 0; ks < 8; ++ks) {
        bf16x8 a[2];
        if (ks < 4) {
            int coff = ks * 32 + lk * 8;
            #pragma unroll
            for (int mf = 0; mf < 2; ++mf) {
                int row = r0 + mf * 16 + lr;
                if (row >= N_NODES) row = N_NODES - 1;
                a[mf] = *reinterpret_cast<const bf16x8*>(
                    xh + (size_t)row * DIM + coff);
            }
        } else {
            int ucoff = (ks - 4) * 16 + lk * 4;
            #pragma unroll
            for (int mf = 0; mf < 2; ++mf) {
                int row = mf * 16 + lr;
                a[mf] = *reinterpret_cast<const bf16x8*>(
                    &h1s[row * 64 + (ucoff ^ ((row & 7) << 2))]);
            }
        }
        bf16x8 bq = *reinterpret_cast<const bf16x8*>(
            wfrag + ((size_t)((wid * 8 + ks) * 64 + lane)) * 8);
        #pragma unroll
        for (int mf = 0; mf < 2; ++mf)
            acc[mf] = __builtin_amdgcn_mfma_f32_16x16x32_bf16(
                a[mf], bq, acc[mf], 0, 0, 0);
    }

    #pragma unroll
    for (int mf = 0; mf < 2; ++mf) {
        int col = wid * 16 + lr;
        #pragma unroll
        for (int rr = 0; rr < 4; ++rr) {
            int row = r0 + mf * 16 + lk * 4 + rr;
            if (row < N_NODES)
                out[(size_t)row * DIM + col] = acc[mf][rr];
        }
    }
}

extern "C" void kernel_launch(void* const* d_in, const int* in_sizes, int n_in,
                              void* d_out, int out_size, void* d_ws, size_t ws_size,
                              hipStream_t stream) {
    const float* x    = (const float*)d_in[0];
    const float* W    = (const float*)d_in[1];
    const int*   esrc = (const int*)d_in[2];
    const int*   edst = (const int*)d_in[3];
    const float* eval = (const float*)d_in[4];
    float* out = (float*)d_out;

    // ws layout (~23.8 MB):
    //   xh     : N*DIM bf16            (12.8 MB)
    //   queue  : NPART*QCAP int2       ( 9.6 MB)
    //   counts : T_TILES*NPART ints    ( 1.2 MB)
    //   qcount : NPART ints            ( 6 KB)
    //   wfrag  : 32768 bf16            (64 KB)
    unsigned short* xh  = (unsigned short*)d_ws;
    int2* queue  = (int2*)(xh + (size_t)N_NODES * DIM);
    int*  counts = (int*)(queue + (size_t)NPART * QCAP);
    int*  qcount = counts + (size_t)T_TILES * NPART;
    unsigned short* wfrag = (unsigned short*)(qcount + NPART);

    bincount_kernel<<<T_TILES, 512, 0, stream>>>(esrc, counts);
    scan_xconv_wconv_kernel<<<NPART + XB + WCONV_B, 256, 0, stream>>>(
        counts, qcount, x, xh, W, wfrag);
    place_kernel<<<T_TILES, 512, 0, stream>>>(esrc, edst, eval, counts, queue);
    gather_gemm_kernel<<<NPART, 512, 0, stream>>>(xh, queue, qcount, wfrag, out);
}